// Round 10
// baseline (647.497 us; speedup 1.0000x reference)
//
#include <hip/hip_runtime.h>
#include <math.h>

#define BB 4096
#define CC 32
#define TT 512
#define NOUTC 16
#define EPSF 1e-5f
#define XS 520   // bf16 row stride in shorts for k3 x_s

// ws layout (floats):
// 0..31: BN1 scale  32..63: BN1 shift (k2)   64..95: BN2 scale  96..127: BN2 shift (k4)
// 128: gcf bf16 frags u16[8192] (4096 floats)
// 4224: hT[32][4096] (131072)
// 135296: part[64][4][4096] (1048576)  -- per-warp BN1 stat partials
// 1183872: x2h bf16-pairs as u32 [4096][8192] (128 MB), MFMA-epilogue order

typedef __attribute__((ext_vector_type(16))) float f32x16;
typedef __attribute__((ext_vector_type(4)))  float f32x4;
typedef __attribute__((ext_vector_type(8)))  short short8;
typedef __attribute__((ext_vector_type(8)))  _Float16 half8;
typedef __attribute__((ext_vector_type(4)))  unsigned int u32x4;
typedef __attribute__((ext_vector_type(2)))  unsigned int u32x2;
typedef __attribute__((ext_vector_type(2)))  float vf2;
typedef __attribute__((ext_vector_type(4)))  float vf4;
typedef vf4 __attribute__((aligned(4))) vf4u;
typedef vf2 __attribute__((aligned(4))) vf2u;

__device__ __forceinline__ unsigned short f2b(float f) {
  unsigned int u = __builtin_bit_cast(unsigned int, f);
  return (unsigned short)((u + 0x7FFFu + ((u >> 16) & 1u)) >> 16);
}
__device__ __forceinline__ float blo(unsigned int u) {
  return __builtin_bit_cast(float, u << 16);
}
__device__ __forceinline__ float bhi(unsigned int u) {
  return __builtin_bit_cast(float, u & 0xFFFF0000u);
}
__device__ __forceinline__ unsigned int pk2(float a, float b) {
  return (unsigned int)f2b(a) | ((unsigned int)f2b(b) << 16);
}
__device__ __forceinline__ unsigned short h16(float f) {
  _Float16 h = (_Float16)f;
  return __builtin_bit_cast(unsigned short, h);
}
__device__ __forceinline__ unsigned int h2pk(float a, float b) {
  return (unsigned int)h16(a) | ((unsigned int)h16(b) << 16);
}

// depthwise conv (k3 fallback path only)
__device__ __forceinline__ void conv_cols(const float* __restrict__ deb,
    const float* __restrict__ dw, const float* __restrict__ db_,
    int tid, float* x1A, float* x1B) {
  int t0 = tid * 2;
  int off = (tid == 0) ? 0 : ((tid == 255) ? t0 - 2 : t0 - 1);
#pragma unroll
  for (int c = 0; c < CC; c++) {
    vf4u v = *reinterpret_cast<const vf4u*>(deb + c * TT + off);
    float vm1 = (tid == 0) ? 0.f : ((tid == 255) ? v.y : v.x);
    float v0  = (tid == 0) ? v.x : ((tid == 255) ? v.z : v.y);
    float vp1 = (tid == 0) ? v.y : ((tid == 255) ? v.w : v.z);
    float vp2 = (tid == 0) ? v.z : ((tid == 255) ? 0.f : v.w);
    float w0 = dw[c * 3], w1 = dw[c * 3 + 1], w2 = dw[c * 3 + 2], bc = db_[c];
    x1A[c] = fmaf(w0, vm1, fmaf(w1, v0, fmaf(w2, vp1, bc)));
    x1B[c] = fmaf(w0, v0, fmaf(w1, vp1, fmaf(w2, vp2, bc)));
  }
}

// load A-fragments: af[k][s] = fp16(pw[o=m31][c] * dw[c][k]), c = s*16+kh*8+j
__device__ __forceinline__ void load_af(half8 af[3][2], const float* __restrict__ pw,
                                        const float* __restrict__ dw, int m31, int kh) {
#pragma unroll
  for (int s = 0; s < 2; s++) {
#pragma unroll
    for (int j = 0; j < 8; j++) {
      int c = s * 16 + kh * 8 + j;
      float pv = pw[m31 * CC + c];
#pragma unroll
      for (int k = 0; k < 3; k++) af[k][s][j] = (_Float16)(pv * dw[c * 3 + k]);
    }
  }
}

// ---------------- kernel 1: fused conv+pointwise 3-tap MFMA, 2-sample rolling pipeline ------
__global__ __launch_bounds__(256, 3) void k1_stats(const float* __restrict__ de,
    const float* __restrict__ dw, const float* __restrict__ db_,
    const float* __restrict__ pw, const float* __restrict__ pwb,
    float* __restrict__ part, unsigned int* __restrict__ x2h, int useWs) {
  __shared__ __align__(16) unsigned short ldsX[2][258 * 40];   // 41280 B
  __shared__ float pbe_s[CC];

  int tid = threadIdx.x, blk = blockIdx.x;   // 0..2047
  int lane = tid & 63, w = tid >> 6;
  int m31 = lane & 31, kh = lane >> 5;
  int rq = tid & 63;                         // wave-local quad index
  int c0 = 8 * w;                            // channel base (uniform per wave)

  half8 af[3][2];
  load_af(af, pw, dw, m31, kh);
  if (tid < CC) {
    float s = pwb[tid];
#pragma unroll
    for (int c = 0; c < CC; c++) s = fmaf(pw[tid * CC + c], db_[c], s);
    pbe_s[tid] = s;
  }
  // static edge zeros: buf0 row0 (t=-1), buf1 row257 (t=512)
  if (tid < 32) { ldsX[0][tid] = 0; ldsX[1][257 * 40 + tid] = 0; }

  // prologue: load both halves of sample blk, stage h0
  vf4 R0[8], R1[8];
  {
    const float* de0 = de + (size_t)blk * CC * TT;
#pragma unroll
    for (int cc = 0; cc < 8; cc++) {
      R0[cc] = *(const vf4u*)(de0 + (c0 + cc) * TT + 4 * rq);
      R1[cc] = *(const vf4u*)(de0 + (c0 + cc) * TT + 256 + 4 * rq);
    }
#pragma unroll
    for (int cc = 0; cc < 8; cc += 2) {
#pragma unroll
      for (int j = 0; j < 4; j++)
        *(unsigned int*)&ldsX[0][(4 * rq + 1 + j) * 40 + c0 + cc] = h2pk(R0[cc][j], R0[cc + 1][j]);
    }
  }

  float sA[16], qA[16];
#pragma unroll
  for (int r = 0; r < 16; r++) { sA[r] = 0.f; qA[r] = 0.f; }

  // compute helper: one half (h) of the current sample from buffer xf
  auto COMPUTE = [&](const unsigned short* xf, int h, unsigned int* xw) {
#pragma unroll
    for (int i = 0; i < 2; i++) {
      int wt = w * 2 + i;
      f32x16 acc;
#pragma unroll
      for (int r = 0; r < 16; r++) acc[r] = 0.f;
      int rowb = wt * 32 + m31;
#pragma unroll
      for (int k = 0; k < 3; k++) {
#pragma unroll
        for (int s = 0; s < 2; s++) {
          half8 bf = *(const half8*)&xf[(rowb + k) * 40 + s * 16 + kh * 8];
          acc = __builtin_amdgcn_mfma_f32_32x32x16_f16(af[k][s], bf, acc, 0, 0, 0);
        }
      }
#pragma unroll
      for (int q4 = 0; q4 < 4; q4++) {
        int ob = 8 * q4 + 4 * kh;
        float v0 = acc[4 * q4 + 0] + pbe_s[ob + 0];
        float v1 = acc[4 * q4 + 1] + pbe_s[ob + 1];
        float v2 = acc[4 * q4 + 2] + pbe_s[ob + 2];
        float v3 = acc[4 * q4 + 3] + pbe_s[ob + 3];
        sA[4 * q4 + 0] += v0; qA[4 * q4 + 0] = fmaf(v0, v0, qA[4 * q4 + 0]);
        sA[4 * q4 + 1] += v1; qA[4 * q4 + 1] = fmaf(v1, v1, qA[4 * q4 + 1]);
        sA[4 * q4 + 2] += v2; qA[4 * q4 + 2] = fmaf(v2, v2, qA[4 * q4 + 2]);
        sA[4 * q4 + 3] += v3; qA[4 * q4 + 3] = fmaf(v3, v3, qA[4 * q4 + 3]);
        if (useWs) {
          u32x2 pr2;
          pr2[0] = pk2(v0, v1);
          pr2[1] = pk2(v2, v3);
          *(u32x2*)(xw + ((((size_t)h * 8 + wt) * 4 + q4) * 2 + kh) * 64 + m31 * 2) = pr2;
        }
      }
    }
  };

  for (int s = 0; s < 2; ++s) {
    size_t b_s = (size_t)blk + (size_t)s * 2048;
    unsigned int* xw = x2h + b_s * (CC * 256);

    // ---- even phase: finish this sample's buffers, prefetch next h0 ----
    __syncthreads();   // prev compute(buf1) done (or prologue)
    // stage h1 rows 1..256 from R1
#pragma unroll
    for (int cc = 0; cc < 8; cc += 2) {
#pragma unroll
      for (int j = 0; j < 4; j++)
        *(unsigned int*)&ldsX[1][(4 * rq + 1 + j) * 40 + c0 + cc] = h2pk(R1[cc][j], R1[cc + 1][j]);
    }
    if (rq == 63) {   // row0 of h1 = t=255 (h0 regs, j=3)
#pragma unroll
      for (int cc = 0; cc < 8; cc += 2)
        *(unsigned int*)&ldsX[1][c0 + cc] = h2pk(R0[cc][3], R0[cc + 1][3]);
    }
    if (rq == 0) {    // row257 of h0 = t=256 (h1 regs, j=0)
#pragma unroll
      for (int cc = 0; cc < 8; cc += 2)
        *(unsigned int*)&ldsX[0][257 * 40 + c0 + cc] = h2pk(R1[cc][0], R1[cc + 1][0]);
    }
    if (s < 1) {      // prefetch next sample h0 into R0 (R0 consumed above)
      const float* den = de + ((size_t)blk + 2048) * CC * TT;
#pragma unroll
      for (int cc = 0; cc < 8; cc++)
        R0[cc] = *(const vf4u*)(den + (c0 + cc) * TT + 4 * rq);
    }
    __syncthreads();
    COMPUTE(ldsX[0], 0, xw);

    // ---- odd phase: stage next sample h0, prefetch next h1 ----
    __syncthreads();   // compute(buf0) done before overwriting it
    if (s < 1) {
#pragma unroll
      for (int cc = 0; cc < 8; cc += 2) {
#pragma unroll
        for (int j = 0; j < 4; j++)
          *(unsigned int*)&ldsX[0][(4 * rq + 1 + j) * 40 + c0 + cc] = h2pk(R0[cc][j], R0[cc + 1][j]);
      }
      const float* den = de + ((size_t)blk + 2048) * CC * TT;
#pragma unroll
      for (int cc = 0; cc < 8; cc++)
        R1[cc] = *(const vf4u*)(den + (c0 + cc) * TT + 256 + 4 * rq);
    }
    __syncthreads();
    COMPUTE(ldsX[1], 1, xw);

    // ---- stats for sample b_s: 32-lane reduce, per-warp partials to part ----
#pragma unroll
    for (int r = 0; r < 16; r++) {
      float ss = sA[r], qq = qA[r];
#pragma unroll
      for (int d = 1; d < 32; d <<= 1) { ss += __shfl_xor(ss, d); qq += __shfl_xor(qq, d); }
      if (m31 == 0) {
        int o = (r & 3) + 8 * (r >> 2) + 4 * kh;
        part[((size_t)o * 4 + w) * BB + b_s] = ss;
        part[(((size_t)(32 + o)) * 4 + w) * BB + b_s] = qq;
      }
      sA[r] = 0.f; qA[r] = 0.f;
    }
  }
}

// ---------------- kernel 2: finalize BN1 scale/shift + gc fragment precompute ----------------
__global__ void k2_bn1(const float* __restrict__ part, const float* __restrict__ g,
                       const float* __restrict__ bta, float* __restrict__ ws,
                       const float* __restrict__ gcw, unsigned short* __restrict__ gcf) {
  __shared__ float redS[256], redQ[256];
  int o = blockIdx.x, tid = threadIdx.x;
  {
    int i = o * 256 + tid;              // 0..8191
    int e = i & 7, ln = (i >> 3) & 63, j = (i >> 9) & 7, w2 = i >> 12;
    int q = ln >> 4, n16 = ln & 15;
    int t = w2 * 256 + q * 8 + j * 32 + e;
    gcf[i] = f2b(gcw[t * 16 + n16]);
  }
  const float* ps = part + (size_t)o * 4 * BB;
  const float* pq = part + (size_t)(CC + o) * 4 * BB;
  float s = 0, q = 0;
  for (int i = tid; i < 4 * BB; i += 256) { s += ps[i]; q += pq[i]; }
  redS[tid] = s; redQ[tid] = q;
  __syncthreads();
  for (int k = 128; k > 0; k >>= 1) {
    if (tid < k) { redS[tid] += redS[tid + k]; redQ[tid] += redQ[tid + k]; }
    __syncthreads();
  }
  if (tid == 0) {
    float N = (float)BB * (float)TT;
    float mean = redS[0] / N;
    float var = redQ[0] / N - mean * mean;
    float sc = g[o] / sqrtf(var + EPSF);
    ws[o] = sc;
    ws[32 + o] = bta[o] - mean * sc;
  }
}

// ---------------- kernel 3: per-sample main pipeline (MFMA Gram + Z) ----------------
__global__ __launch_bounds__(256, 3) void k3_main(const float* __restrict__ de,
    const float* __restrict__ dw, const float* __restrict__ db_,
    const float* __restrict__ pw, const float* __restrict__ pwb,
    const float* __restrict__ wsv, const unsigned short* __restrict__ gcf,
    const float* __restrict__ fcw, const float* __restrict__ fcb,
    float* __restrict__ hT, const unsigned int* __restrict__ x2h, int useWs) {
  __shared__ __align__(16) unsigned short x_s[CC * XS];   // 33280 B
  __shared__ float gramP[2][CC * CC];                     // [0] reused as num, [1] as red2
  __shared__ float zP[2][CC * NOUTC];                     // [0] reused as Zi, [1] as g2
  __shared__ float red16[CC * 8];
  __shared__ float mu_s[CC], inv_s[CC];
  __shared__ float scsh[64];

  int tid = threadIdx.x, b = blockIdx.x;
  int w = tid >> 6, lane = tid & 63;
  int t0 = tid * 2;

  if (tid < 64) scsh[tid] = wsv[tid];
  __syncthreads();

  if (useWs) {
    const unsigned int* xr = x2h + (size_t)b * (CC * 256);
#pragma unroll
    for (int it = 0; it < 16; it++) {
      int g = it * 256 + tid;
      int m31g = g & 31, khg = (g >> 5) & 1, q4g = (g >> 6) & 3;
      int wtg = (g >> 8) & 7, hg = (g >> 11) & 1;
      u32x2 v = *(const u32x2*)(xr + (size_t)g * 2);
      int ob = 8 * q4g + 4 * khg;
      int t = hg * 256 + wtg * 32 + m31g;
      float f0 = fmaxf(fmaf(blo(v[0]), scsh[ob + 0], scsh[32 + ob + 0]), 0.f);
      float f1 = fmaxf(fmaf(bhi(v[0]), scsh[ob + 1], scsh[32 + ob + 1]), 0.f);
      float f2 = fmaxf(fmaf(blo(v[1]), scsh[ob + 2], scsh[32 + ob + 2]), 0.f);
      float f3 = fmaxf(fmaf(bhi(v[1]), scsh[ob + 3], scsh[32 + ob + 3]), 0.f);
      x_s[(ob + 0) * XS + t] = f2b(f0);
      x_s[(ob + 1) * XS + t] = f2b(f1);
      x_s[(ob + 2) * XS + t] = f2b(f2);
      x_s[(ob + 3) * XS + t] = f2b(f3);
    }
  } else {
    // fallback: recompute conv + pointwise (scalar)
    const float* deb = de + (size_t)b * CC * TT;
    float x1A[CC], x1B[CC];
    conv_cols(deb, dw, db_, tid, x1A, x1B);
#pragma unroll
    for (int o = 0; o < CC; o++) {
      float aA = pwb[o], aB = pwb[o];
#pragma unroll
      for (int c = 0; c < CC; c++) { float pv = pw[o * CC + c]; aA = fmaf(pv, x1A[c], aA); aB = fmaf(pv, x1B[c], aB); }
      float sc = scsh[o], sh = scsh[32 + o];
      unsigned short hA = f2b(fmaxf(fmaf(aA, sc, sh), 0.f));
      unsigned short hB = f2b(fmaxf(fmaf(aB, sc, sh), 0.f));
      *(unsigned int*)(&x_s[o * XS + t0]) = (unsigned int)hA | ((unsigned int)hB << 16);
    }
  }
  __syncthreads();

  // mu partials: strided LDS re-read of x_s
  {
    int c = tid >> 3, j = tid & 7;
    float s = 0.f;
#pragma unroll
    for (int it = 0; it < 8; it++) {
      u32x4 u = *reinterpret_cast<const u32x4*>(&x_s[c * XS + j * 64 + it * 8]);
#pragma unroll
      for (int k = 0; k < 4; k++) s += blo(u[k]) + bhi(u[k]);
    }
    red16[c * 8 + j] = s;
  }

  // MFMA: waves 0,1 = Gram halves (32x32x16); waves 2,3 = Z halves (16x16x32)
  if (w < 2) {
    int m = lane & 31, kh = lane >> 5;
    f32x16 acc;
#pragma unroll
    for (int r = 0; r < 16; r++) acc[r] = 0.f;
    int kbase = w * 256 + kh * 8;
#pragma unroll
    for (int kk = 0; kk < 256; kk += 16) {
      short8 a = *(const short8*)(&x_s[m * XS + kbase + kk]);
      acc = __builtin_amdgcn_mfma_f32_32x32x16_bf16(a, a, acc, 0, 0, 0);
    }
#pragma unroll
    for (int r = 0; r < 16; r++) {
      int row = (r & 3) + 8 * (r >> 2) + 4 * kh;
      gramP[w][row * CC + m] = acc[r];
    }
  } else {
    int w2 = w - 2;
    int n16 = lane & 15, q = lane >> 4;
    f32x4 ac0, ac1;
#pragma unroll
    for (int r = 0; r < 4; r++) { ac0[r] = 0.f; ac1[r] = 0.f; }
    const unsigned short* gf = gcf + w2 * 4096;
    short8 bfr[8];
#pragma unroll
    for (int j = 0; j < 8; j++) bfr[j] = *(const short8*)(gf + (j * 64 + lane) * 8);
    int kbase = w2 * 256 + q * 8;
#pragma unroll
    for (int j = 0; j < 8; j++) {
      int kk = j * 32;
      short8 af0 = *(const short8*)(&x_s[n16 * XS + kbase + kk]);
      short8 af1 = *(const short8*)(&x_s[(16 + n16) * XS + kbase + kk]);
      ac0 = __builtin_amdgcn_mfma_f32_16x16x32_bf16(af0, bfr[j], ac0, 0, 0, 0);
      ac1 = __builtin_amdgcn_mfma_f32_16x16x32_bf16(af1, bfr[j], ac1, 0, 0, 0);
    }
#pragma unroll
    for (int r = 0; r < 4; r++) {
      int row = q * 4 + r;
      zP[w2][row * NOUTC + n16] = ac0[r];
      zP[w2][(16 + row) * NOUTC + n16] = ac1[r];
    }
  }
  __syncthreads();
  if (tid < CC) {
    float s = 0.f;
#pragma unroll
    for (int j = 0; j < 8; j++) s += red16[tid * 8 + j];
    mu_s[tid] = s;
  }
  __syncthreads();
  float* gram0 = gramP[0];
  float* Zi = zP[0];
  float* g2 = zP[1];
  for (int i = tid; i < CC * CC; i += 256) {
    int n = i >> 5, m = i & 31;
    gram0[i] = gram0[i] + gramP[1][i] - mu_s[n] * mu_s[m] * (1.f / (float)TT);
  }
  for (int i = tid; i < CC * NOUTC; i += 256) Zi[i] = zP[0][i] + zP[1][i];
  __syncthreads();
  if (tid < CC) inv_s[tid] = rsqrtf(gram0[tid * 32 + tid]);
  __syncthreads();
  for (int i = tid; i < CC * NOUTC; i += 256) {
    int n = i >> 4, o = i & 15;
    float s = 0.f;
#pragma unroll
    for (int m = 0; m < CC; m++) s = fmaf(gram0[n * 32 + m] * inv_s[m], Zi[m * NOUTC + o], s);
    g2[i] = fmaxf(s * inv_s[n], 0.f);
  }
  __syncthreads();
  float* red2 = gramP[1];
  {
    int j = tid & 31, ch = tid >> 5;
    float pacc = 0.f;
#pragma unroll
    for (int ii = 0; ii < 64; ii++) {
      int i = ch * 64 + ii;
      pacc = fmaf(g2[i], fcw[i * CC + j], pacc);
    }
    red2[j * 9 + ch] = pacc;
  }
  __syncthreads();
  if (tid < CC) {
    float h = fcb[tid];
#pragma unroll
    for (int ch = 0; ch < 8; ch++) h += red2[tid * 9 + ch];
    hT[(size_t)tid * BB + b] = h;
  }
}

// ---------------- kernel 4: BN2 stats ----------------
__global__ void k4_bn2(const float* __restrict__ hT, const float* __restrict__ g,
                       const float* __restrict__ bta, float* __restrict__ ws) {
  __shared__ float redS[256], redQ[256];
  int j = blockIdx.x, tid = threadIdx.x;
  const float* row = hT + (size_t)j * BB;
  float s = 0, q = 0;
  for (int i = tid; i < BB; i += 256) { float v = row[i]; s += v; q = fmaf(v, v, q); }
  redS[tid] = s; redQ[tid] = q;
  __syncthreads();
  for (int k = 128; k > 0; k >>= 1) {
    if (tid < k) { redS[tid] += redS[tid + k]; redQ[tid] += redQ[tid + k]; }
    __syncthreads();
  }
  if (tid == 0) {
    float N = (float)BB;
    float mean = redS[0] / N;
    float var = redQ[0] / N - mean * mean;
    float sc = g[j] / sqrtf(var + EPSF);
    ws[64 + j] = sc;
    ws[96 + j] = bta[j] - mean * sc;
  }
}

// ---------------- kernel 5: BN2 apply + sigmoid + classifier ----------------
__global__ void k5_out(const float* __restrict__ hT, const float* __restrict__ ws,
                       const float* __restrict__ clsw, const float* __restrict__ clsb,
                       float* __restrict__ out) {
  __shared__ float hs[CC * 257];
  int b0 = blockIdx.x * 256, tid = threadIdx.x;
  for (int i = tid; i < CC * 256; i += 256) {
    int j = i >> 8, bb = i & 255;
    float v = fmaf(hT[(size_t)j * BB + b0 + bb], ws[64 + j], ws[96 + j]);
    hs[j * 257 + bb] = 1.f / (1.f + expf(-v));
  }
  __syncthreads();
  float o0 = clsb[0], o1 = clsb[1], o2 = clsb[2], o3 = clsb[3];
#pragma unroll
  for (int j = 0; j < CC; j++) {
    float h = hs[j * 257 + tid];
    o0 = fmaf(h, clsw[j * 4 + 0], o0);
    o1 = fmaf(h, clsw[j * 4 + 1], o1);
    o2 = fmaf(h, clsw[j * 4 + 2], o2);
    o3 = fmaf(h, clsw[j * 4 + 3], o3);
  }
  float4* out4 = reinterpret_cast<float4*>(out);
  out4[b0 + tid] = make_float4(o0, o1, o2, o3);
}

extern "C" void kernel_launch(void* const* d_in, const int* in_sizes, int n_in,
                              void* d_out, int out_size, void* d_ws, size_t ws_size,
                              hipStream_t stream) {
  const float* de   = (const float*)d_in[0];
  const float* dw   = (const float*)d_in[2];
  const float* db_  = (const float*)d_in[3];
  const float* pw   = (const float*)d_in[4];
  const float* pwb  = (const float*)d_in[5];
  const float* bn1g = (const float*)d_in[6];
  const float* bn1b = (const float*)d_in[7];
  const float* gcw  = (const float*)d_in[8];
  const float* fcw  = (const float*)d_in[9];
  const float* fcb  = (const float*)d_in[10];
  const float* bn2g = (const float*)d_in[11];
  const float* bn2b = (const float*)d_in[12];
  const float* clsw = (const float*)d_in[13];
  const float* clsb = (const float*)d_in[14];

  float* ws = (float*)d_ws;
  unsigned short* gcf = (unsigned short*)(ws + 128);
  float* hT   = ws + 4224;
  float* part = ws + 135296;
  unsigned int* x2h = (unsigned int*)(ws + 1183872);
  float* out  = (float*)d_out;

  size_t need = ((size_t)1183872 + 33554432ull) * 4ull;  // ~138.9 MB
  int useWs = (ws_size >= need) ? 1 : 0;

  k1_stats<<<2048, 256, 0, stream>>>(de, dw, db_, pw, pwb, part, x2h, useWs);
  k2_bn1<<<CC, 256, 0, stream>>>(part, bn1g, bn1b, ws, gcw, gcf);
  k3_main<<<BB, 256, 0, stream>>>(de, dw, db_, pw, pwb, ws, gcf, fcw, fcb, hT, x2h, useWs);
  k4_bn2<<<CC, 256, 0, stream>>>(hT, bn2g, bn2b, ws);
  k5_out<<<BB / 256, 256, 0, stream>>>(hT, ws, clsw, clsb, out);
}

// Round 11
// 470.282 us; speedup vs baseline: 1.3768x; 1.3768x over previous
//
#include <hip/hip_runtime.h>
#include <math.h>

#define BB 4096
#define CC 32
#define TT 512
#define NOUTC 16
#define EPSF 1e-5f
#define XS 520   // bf16 row stride in shorts for k3 x_s

// ws layout (floats):
// 0..31: BN1 scale  32..63: BN1 shift (k2)   64..95: BN2 scale  96..127: BN2 shift (k4)
// 128: gcf bf16 frags u16[8192] (4096 floats)
// 4224: hT[32][4096] (131072)
// 135296: part[64][4096] (262144)
// 397440: x2h bf16-pairs as u32 [4096][8192] (128 MB), MFMA-epilogue order

typedef __attribute__((ext_vector_type(16))) float f32x16;
typedef __attribute__((ext_vector_type(4)))  float f32x4;
typedef __attribute__((ext_vector_type(8)))  short short8;
typedef __attribute__((ext_vector_type(8)))  _Float16 half8;
typedef __attribute__((ext_vector_type(4)))  unsigned int u32x4;
typedef __attribute__((ext_vector_type(2)))  unsigned int u32x2;
typedef __attribute__((ext_vector_type(2)))  float vf2;
typedef __attribute__((ext_vector_type(4)))  float vf4;
typedef vf4 __attribute__((aligned(4))) vf4u;
typedef vf2 __attribute__((aligned(4))) vf2u;

__device__ __forceinline__ unsigned short f2b(float f) {
  unsigned int u = __builtin_bit_cast(unsigned int, f);
  return (unsigned short)((u + 0x7FFFu + ((u >> 16) & 1u)) >> 16);
}
__device__ __forceinline__ float blo(unsigned int u) {
  return __builtin_bit_cast(float, u << 16);
}
__device__ __forceinline__ float bhi(unsigned int u) {
  return __builtin_bit_cast(float, u & 0xFFFF0000u);
}
__device__ __forceinline__ unsigned int pk2(float a, float b) {
  return (unsigned int)f2b(a) | ((unsigned int)f2b(b) << 16);
}
__device__ __forceinline__ unsigned short h16(float f) {
  _Float16 h = (_Float16)f;
  return __builtin_bit_cast(unsigned short, h);
}
__device__ __forceinline__ unsigned int h2pk(float a, float b) {
  return (unsigned int)h16(a) | ((unsigned int)h16(b) << 16);
}

// depthwise conv (k3 fallback path only)
__device__ __forceinline__ void conv_cols(const float* __restrict__ deb,
    const float* __restrict__ dw, const float* __restrict__ db_,
    int tid, float* x1A, float* x1B) {
  int t0 = tid * 2;
  int off = (tid == 0) ? 0 : ((tid == 255) ? t0 - 2 : t0 - 1);
#pragma unroll
  for (int c = 0; c < CC; c++) {
    vf4u v = *reinterpret_cast<const vf4u*>(deb + c * TT + off);
    float vm1 = (tid == 0) ? 0.f : ((tid == 255) ? v.y : v.x);
    float v0  = (tid == 0) ? v.x : ((tid == 255) ? v.z : v.y);
    float vp1 = (tid == 0) ? v.y : ((tid == 255) ? v.w : v.z);
    float vp2 = (tid == 0) ? v.z : ((tid == 255) ? 0.f : v.w);
    float w0 = dw[c * 3], w1 = dw[c * 3 + 1], w2 = dw[c * 3 + 2], bc = db_[c];
    x1A[c] = fmaf(w0, vm1, fmaf(w1, v0, fmaf(w2, vp1, bc)));
    x1B[c] = fmaf(w0, v0, fmaf(w1, vp1, fmaf(w2, vp2, bc)));
  }
}

// load A-fragments: af[k][s] = fp16(pw[o=m31][c] * dw[c][k]), c = s*16+kh*8+j
__device__ __forceinline__ void load_af(half8 af[3][2], const float* __restrict__ pw,
                                        const float* __restrict__ dw, int m31, int kh) {
#pragma unroll
  for (int s = 0; s < 2; s++) {
#pragma unroll
    for (int j = 0; j < 8; j++) {
      int c = s * 16 + kh * 8 + j;
      float pv = pw[m31 * CC + c];
#pragma unroll
      for (int k = 0; k < 3; k++) af[k][s][j] = (_Float16)(pv * dw[c * 3 + k]);
    }
  }
}

// issue main-row loads of one half into regs: 16 x dwordx2 (chans 16p..16p+15, rows 2rp,2rp+1)
__device__ __forceinline__ void load_half(const float* __restrict__ deb, int h, int p, int rp,
                                          vf2 r[16]) {
  int t0 = h * 256 + 2 * rp - 1;
  int tl = (t0 < 0) ? 0 : t0;
#pragma unroll
  for (int cc = 0; cc < 16; cc++) {
    int c = 16 * p + cc;
    r[cc] = *(const vf2u*)(deb + c * TT + tl);
  }
}

// write one half's regs into XF buffer ([t][c] fp16, rows 0..255, stride 40)
__device__ __forceinline__ void write_half(unsigned short* xf, vf2 r[16], int h, int p, int rp) {
  int t0 = h * 256 + 2 * rp - 1;
  int r0 = 2 * rp;
#pragma unroll
  for (int cc = 0; cc < 16; cc += 2) {
    int c = 16 * p + cc;
    vf2 va = r[cc], vb = r[cc + 1];
    if (t0 < 0) { va.y = va.x; va.x = 0.f; vb.y = vb.x; vb.x = 0.f; }
    *(unsigned int*)&xf[r0 * 40 + c] = h2pk(va.x, vb.x);
    *(unsigned int*)&xf[(r0 + 1) * 40 + c] = h2pk(va.y, vb.y);
  }
}

// ---------------- kernel 1: fused conv+pointwise 3-tap MFMA, split-phase overlap ----------------
__global__ __launch_bounds__(256, 3) void k1_stats(const float* __restrict__ de,
    const float* __restrict__ dw, const float* __restrict__ db_,
    const float* __restrict__ pw, const float* __restrict__ pwb,
    float* __restrict__ part, unsigned int* __restrict__ x2h, int useWs) {
  __shared__ __align__(16) unsigned short ldsX[2][258 * 40];   // 41280 B
  __shared__ float pbe_s[CC];
  __shared__ float sqb[4][64];

  int tid = threadIdx.x, b = blockIdx.x;
  int lane = tid & 63, w = tid >> 6;
  int m31 = lane & 31, kh = lane >> 5;
  int p = tid >> 7, rp = tid & 127;

  const float* deb = de + (size_t)b * CC * TT;

  // ---- issue ALL global loads upfront (32 x dwordx2 + edge scalars in flight) ----
  vf2 rA[16], rB[16];
  load_half(deb, 0, p, rp, rA);
  load_half(deb, 1, p, rp, rB);
  // edge rows 256,257 of each half, distributed: tid<128, 1 scalar each
  int eh = tid >> 6, ej = (tid >> 5) & 1, ec = tid & 31;
  int et = eh * 256 + 255 + ej;
  float ev = 0.f;
  if (tid < 128 && et < TT) ev = deb[ec * TT + et];

  half8 af[3][2];
  load_af(af, pw, dw, m31, kh);
  if (tid < CC) {
    float s = pwb[tid];
#pragma unroll
    for (int c = 0; c < CC; c++) s = fmaf(pw[tid * CC + c], db_[c], s);
    pbe_s[tid] = s;
  }

  unsigned int* xw = x2h + (size_t)b * (CC * 256);
  float sA[16], qA[16];
#pragma unroll
  for (int r = 0; r < 16; r++) { sA[r] = 0.f; qA[r] = 0.f; }

  // ---- stage h0 only (waits only rA); h1 loads stay in flight ----
  write_half(ldsX[0], rA, 0, p, rp);
  if (tid < 64) ldsX[0][(256 + ej) * 40 + ec] = h16(ev);   // h0 rows 256,257
  __syncthreads();

  // ---- compute h0 (rB still in registers/in flight), then stage h1, then compute h1 ----
#pragma unroll
  for (int h = 0; h < 2; h++) {
    if (h == 1) {
      // stage h1 after h0's compute: the vmcnt wait for rB hid under h0's MFMAs
      write_half(ldsX[1], rB, 1, p, rp);
      if (tid >= 64 && tid < 128) ldsX[1][(256 + ej) * 40 + ec] = h16(ev);  // h1 rows 256,257
      __syncthreads();
    }
    const unsigned short* xf = ldsX[h];
#pragma unroll
    for (int i = 0; i < 2; i++) {
      int wt = w * 2 + i;
      f32x16 acc;
#pragma unroll
      for (int r = 0; r < 16; r++) acc[r] = 0.f;
      int rowb = wt * 32 + m31;
#pragma unroll
      for (int k = 0; k < 3; k++) {
#pragma unroll
        for (int s = 0; s < 2; s++) {
          half8 bf = *(const half8*)&xf[(rowb + k) * 40 + s * 16 + kh * 8];
          acc = __builtin_amdgcn_mfma_f32_32x32x16_f16(af[k][s], bf, acc, 0, 0, 0);
        }
      }
      // epilogue: +bias, stats in regs, direct coalesced x2h store
#pragma unroll
      for (int q4 = 0; q4 < 4; q4++) {
        int ob = 8 * q4 + 4 * kh;
        float v0 = acc[4 * q4 + 0] + pbe_s[ob + 0];
        float v1 = acc[4 * q4 + 1] + pbe_s[ob + 1];
        float v2 = acc[4 * q4 + 2] + pbe_s[ob + 2];
        float v3 = acc[4 * q4 + 3] + pbe_s[ob + 3];
        sA[4 * q4 + 0] += v0; qA[4 * q4 + 0] = fmaf(v0, v0, qA[4 * q4 + 0]);
        sA[4 * q4 + 1] += v1; qA[4 * q4 + 1] = fmaf(v1, v1, qA[4 * q4 + 1]);
        sA[4 * q4 + 2] += v2; qA[4 * q4 + 2] = fmaf(v2, v2, qA[4 * q4 + 2]);
        sA[4 * q4 + 3] += v3; qA[4 * q4 + 3] = fmaf(v3, v3, qA[4 * q4 + 3]);
        if (useWs) {
          u32x2 pr2;
          pr2[0] = pk2(v0, v1);
          pr2[1] = pk2(v2, v3);
          *(u32x2*)(xw + ((((size_t)h * 8 + wt) * 4 + q4) * 2 + kh) * 64 + m31 * 2) = pr2;
        }
      }
    }
  }

  // stats: reduce over t-lanes (32-lane halves hold disjoint o-sets), combine waves, write part
#pragma unroll
  for (int r = 0; r < 16; r++) {
    float s = sA[r], q = qA[r];
#pragma unroll
    for (int d = 1; d < 32; d <<= 1) { s += __shfl_xor(s, d); q += __shfl_xor(q, d); }
    sA[r] = s; qA[r] = q;
  }
  if (m31 == 0) {
#pragma unroll
    for (int r = 0; r < 16; r++) {
      int o = (r & 3) + 8 * (r >> 2) + 4 * kh;
      sqb[w][o * 2 + 0] = sA[r];
      sqb[w][o * 2 + 1] = qA[r];
    }
  }
  __syncthreads();
  if (tid < 64) {
    int o = tid >> 1, st = tid & 1;
    float v = sqb[0][tid] + sqb[1][tid] + sqb[2][tid] + sqb[3][tid];
    part[(size_t)(st * 32 + o) * BB + b] = v;
  }
}

// ---------------- kernel 2: finalize BN1 scale/shift + gc fragment precompute ----------------
__global__ void k2_bn1(const float* __restrict__ part, const float* __restrict__ g,
                       const float* __restrict__ bta, float* __restrict__ ws,
                       const float* __restrict__ gcw, unsigned short* __restrict__ gcf) {
  __shared__ float redS[256], redQ[256];
  int o = blockIdx.x, tid = threadIdx.x;
  {
    int i = o * 256 + tid;              // 0..8191
    int e = i & 7, ln = (i >> 3) & 63, j = (i >> 9) & 7, w2 = i >> 12;
    int q = ln >> 4, n16 = ln & 15;
    int t = w2 * 256 + q * 8 + j * 32 + e;
    gcf[i] = f2b(gcw[t * 16 + n16]);
  }
  const float* ps = part + (size_t)o * BB;
  const float* pq = part + (size_t)(CC + o) * BB;
  float s = 0, q = 0;
  for (int i = tid; i < BB; i += 256) { s += ps[i]; q += pq[i]; }
  redS[tid] = s; redQ[tid] = q;
  __syncthreads();
  for (int k = 128; k > 0; k >>= 1) {
    if (tid < k) { redS[tid] += redS[tid + k]; redQ[tid] += redQ[tid + k]; }
    __syncthreads();
  }
  if (tid == 0) {
    float N = (float)BB * (float)TT;
    float mean = redS[0] / N;
    float var = redQ[0] / N - mean * mean;
    float sc = g[o] / sqrtf(var + EPSF);
    ws[o] = sc;
    ws[32 + o] = bta[o] - mean * sc;
  }
}

// ---------------- kernel 3: per-sample main pipeline (MFMA Gram + Z) ----------------
__global__ __launch_bounds__(256, 3) void k3_main(const float* __restrict__ de,
    const float* __restrict__ dw, const float* __restrict__ db_,
    const float* __restrict__ pw, const float* __restrict__ pwb,
    const float* __restrict__ wsv, const unsigned short* __restrict__ gcf,
    const float* __restrict__ fcw, const float* __restrict__ fcb,
    float* __restrict__ hT, const unsigned int* __restrict__ x2h, int useWs) {
  __shared__ __align__(16) unsigned short x_s[CC * XS];   // 33280 B
  __shared__ float gramP[2][CC * CC];                     // [0] reused as num, [1] as red2
  __shared__ float zP[2][CC * NOUTC];                     // [0] reused as Zi, [1] as g2
  __shared__ float red16[CC * 8];
  __shared__ float mu_s[CC], inv_s[CC];
  __shared__ float scsh[64];

  int tid = threadIdx.x, b = blockIdx.x;
  int w = tid >> 6, lane = tid & 63;
  int t0 = tid * 2;

  if (tid < 64) scsh[tid] = wsv[tid];
  __syncthreads();

  if (useWs) {
    const unsigned int* xr = x2h + (size_t)b * (CC * 256);
#pragma unroll
    for (int it = 0; it < 16; it++) {
      int g = it * 256 + tid;
      int m31g = g & 31, khg = (g >> 5) & 1, q4g = (g >> 6) & 3;
      int wtg = (g >> 8) & 7, hg = (g >> 11) & 1;
      u32x2 v = *(const u32x2*)(xr + (size_t)g * 2);
      int ob = 8 * q4g + 4 * khg;
      int t = hg * 256 + wtg * 32 + m31g;
      float f0 = fmaxf(fmaf(blo(v[0]), scsh[ob + 0], scsh[32 + ob + 0]), 0.f);
      float f1 = fmaxf(fmaf(bhi(v[0]), scsh[ob + 1], scsh[32 + ob + 1]), 0.f);
      float f2 = fmaxf(fmaf(blo(v[1]), scsh[ob + 2], scsh[32 + ob + 2]), 0.f);
      float f3 = fmaxf(fmaf(bhi(v[1]), scsh[ob + 3], scsh[32 + ob + 3]), 0.f);
      x_s[(ob + 0) * XS + t] = f2b(f0);
      x_s[(ob + 1) * XS + t] = f2b(f1);
      x_s[(ob + 2) * XS + t] = f2b(f2);
      x_s[(ob + 3) * XS + t] = f2b(f3);
    }
  } else {
    // fallback: recompute conv + pointwise (scalar)
    const float* deb = de + (size_t)b * CC * TT;
    float x1A[CC], x1B[CC];
    conv_cols(deb, dw, db_, tid, x1A, x1B);
#pragma unroll
    for (int o = 0; o < CC; o++) {
      float aA = pwb[o], aB = pwb[o];
#pragma unroll
      for (int c = 0; c < CC; c++) { float pv = pw[o * CC + c]; aA = fmaf(pv, x1A[c], aA); aB = fmaf(pv, x1B[c], aB); }
      float sc = scsh[o], sh = scsh[32 + o];
      unsigned short hA = f2b(fmaxf(fmaf(aA, sc, sh), 0.f));
      unsigned short hB = f2b(fmaxf(fmaf(aB, sc, sh), 0.f));
      *(unsigned int*)(&x_s[o * XS + t0]) = (unsigned int)hA | ((unsigned int)hB << 16);
    }
  }
  __syncthreads();

  // mu partials: strided LDS re-read of x_s
  {
    int c = tid >> 3, j = tid & 7;
    float s = 0.f;
#pragma unroll
    for (int it = 0; it < 8; it++) {
      u32x4 u = *reinterpret_cast<const u32x4*>(&x_s[c * XS + j * 64 + it * 8]);
#pragma unroll
      for (int k = 0; k < 4; k++) s += blo(u[k]) + bhi(u[k]);
    }
    red16[c * 8 + j] = s;
  }

  // MFMA: waves 0,1 = Gram halves (32x32x16); waves 2,3 = Z halves (16x16x32)
  if (w < 2) {
    int m = lane & 31, kh = lane >> 5;
    f32x16 acc;
#pragma unroll
    for (int r = 0; r < 16; r++) acc[r] = 0.f;
    int kbase = w * 256 + kh * 8;
#pragma unroll
    for (int kk = 0; kk < 256; kk += 16) {
      short8 a = *(const short8*)(&x_s[m * XS + kbase + kk]);
      acc = __builtin_amdgcn_mfma_f32_32x32x16_bf16(a, a, acc, 0, 0, 0);
    }
#pragma unroll
    for (int r = 0; r < 16; r++) {
      int row = (r & 3) + 8 * (r >> 2) + 4 * kh;
      gramP[w][row * CC + m] = acc[r];
    }
  } else {
    int w2 = w - 2;
    int n16 = lane & 15, q = lane >> 4;
    f32x4 ac0, ac1;
#pragma unroll
    for (int r = 0; r < 4; r++) { ac0[r] = 0.f; ac1[r] = 0.f; }
    const unsigned short* gf = gcf + w2 * 4096;
    short8 bfr[8];
#pragma unroll
    for (int j = 0; j < 8; j++) bfr[j] = *(const short8*)(gf + (j * 64 + lane) * 8);
    int kbase = w2 * 256 + q * 8;
#pragma unroll
    for (int j = 0; j < 8; j++) {
      int kk = j * 32;
      short8 af0 = *(const short8*)(&x_s[n16 * XS + kbase + kk]);
      short8 af1 = *(const short8*)(&x_s[(16 + n16) * XS + kbase + kk]);
      ac0 = __builtin_amdgcn_mfma_f32_16x16x32_bf16(af0, bfr[j], ac0, 0, 0, 0);
      ac1 = __builtin_amdgcn_mfma_f32_16x16x32_bf16(af1, bfr[j], ac1, 0, 0, 0);
    }
#pragma unroll
    for (int r = 0; r < 4; r++) {
      int row = q * 4 + r;
      zP[w2][row * NOUTC + n16] = ac0[r];
      zP[w2][(16 + row) * NOUTC + n16] = ac1[r];
    }
  }
  __syncthreads();
  if (tid < CC) {
    float s = 0.f;
#pragma unroll
    for (int j = 0; j < 8; j++) s += red16[tid * 8 + j];
    mu_s[tid] = s;
  }
  __syncthreads();
  float* gram0 = gramP[0];
  float* Zi = zP[0];
  float* g2 = zP[1];
  for (int i = tid; i < CC * CC; i += 256) {
    int n = i >> 5, m = i & 31;
    gram0[i] = gram0[i] + gramP[1][i] - mu_s[n] * mu_s[m] * (1.f / (float)TT);
  }
  for (int i = tid; i < CC * NOUTC; i += 256) Zi[i] = zP[0][i] + zP[1][i];
  __syncthreads();
  if (tid < CC) inv_s[tid] = rsqrtf(gram0[tid * 32 + tid]);
  __syncthreads();
  for (int i = tid; i < CC * NOUTC; i += 256) {
    int n = i >> 4, o = i & 15;
    float s = 0.f;
#pragma unroll
    for (int m = 0; m < CC; m++) s = fmaf(gram0[n * 32 + m] * inv_s[m], Zi[m * NOUTC + o], s);
    g2[i] = fmaxf(s * inv_s[n], 0.f);
  }
  __syncthreads();
  float* red2 = gramP[1];
  {
    int j = tid & 31, ch = tid >> 5;
    float pacc = 0.f;
#pragma unroll
    for (int ii = 0; ii < 64; ii++) {
      int i = ch * 64 + ii;
      pacc = fmaf(g2[i], fcw[i * CC + j], pacc);
    }
    red2[j * 9 + ch] = pacc;
  }
  __syncthreads();
  if (tid < CC) {
    float h = fcb[tid];
#pragma unroll
    for (int ch = 0; ch < 8; ch++) h += red2[tid * 9 + ch];
    hT[(size_t)tid * BB + b] = h;
  }
}

// ---------------- kernel 4: BN2 stats ----------------
__global__ void k4_bn2(const float* __restrict__ hT, const float* __restrict__ g,
                       const float* __restrict__ bta, float* __restrict__ ws) {
  __shared__ float redS[256], redQ[256];
  int j = blockIdx.x, tid = threadIdx.x;
  const float* row = hT + (size_t)j * BB;
  float s = 0, q = 0;
  for (int i = tid; i < BB; i += 256) { float v = row[i]; s += v; q = fmaf(v, v, q); }
  redS[tid] = s; redQ[tid] = q;
  __syncthreads();
  for (int k = 128; k > 0; k >>= 1) {
    if (tid < k) { redS[tid] += redS[tid + k]; redQ[tid] += redQ[tid + k]; }
    __syncthreads();
  }
  if (tid == 0) {
    float N = (float)BB;
    float mean = redS[0] / N;
    float var = redQ[0] / N - mean * mean;
    float sc = g[j] / sqrtf(var + EPSF);
    ws[64 + j] = sc;
    ws[96 + j] = bta[j] - mean * sc;
  }
}

// ---------------- kernel 5: BN2 apply + sigmoid + classifier ----------------
__global__ void k5_out(const float* __restrict__ hT, const float* __restrict__ ws,
                       const float* __restrict__ clsw, const float* __restrict__ clsb,
                       float* __restrict__ out) {
  __shared__ float hs[CC * 257];
  int b0 = blockIdx.x * 256, tid = threadIdx.x;
  for (int i = tid; i < CC * 256; i += 256) {
    int j = i >> 8, bb = i & 255;
    float v = fmaf(hT[(size_t)j * BB + b0 + bb], ws[64 + j], ws[96 + j]);
    hs[j * 257 + bb] = 1.f / (1.f + expf(-v));
  }
  __syncthreads();
  float o0 = clsb[0], o1 = clsb[1], o2 = clsb[2], o3 = clsb[3];
#pragma unroll
  for (int j = 0; j < CC; j++) {
    float h = hs[j * 257 + tid];
    o0 = fmaf(h, clsw[j * 4 + 0], o0);
    o1 = fmaf(h, clsw[j * 4 + 1], o1);
    o2 = fmaf(h, clsw[j * 4 + 2], o2);
    o3 = fmaf(h, clsw[j * 4 + 3], o3);
  }
  float4* out4 = reinterpret_cast<float4*>(out);
  out4[b0 + tid] = make_float4(o0, o1, o2, o3);
}

extern "C" void kernel_launch(void* const* d_in, const int* in_sizes, int n_in,
                              void* d_out, int out_size, void* d_ws, size_t ws_size,
                              hipStream_t stream) {
  const float* de   = (const float*)d_in[0];
  const float* dw   = (const float*)d_in[2];
  const float* db_  = (const float*)d_in[3];
  const float* pw   = (const float*)d_in[4];
  const float* pwb  = (const float*)d_in[5];
  const float* bn1g = (const float*)d_in[6];
  const float* bn1b = (const float*)d_in[7];
  const float* gcw  = (const float*)d_in[8];
  const float* fcw  = (const float*)d_in[9];
  const float* fcb  = (const float*)d_in[10];
  const float* bn2g = (const float*)d_in[11];
  const float* bn2b = (const float*)d_in[12];
  const float* clsw = (const float*)d_in[13];
  const float* clsb = (const float*)d_in[14];

  float* ws = (float*)d_ws;
  unsigned short* gcf = (unsigned short*)(ws + 128);
  float* hT   = ws + 4224;
  float* part = ws + 135296;
  unsigned int* x2h = (unsigned int*)(ws + 397440);
  float* out  = (float*)d_out;

  size_t need = ((size_t)397440 + 33554432ull) * 4ull;  // ~135.8 MB
  int useWs = (ws_size >= need) ? 1 : 0;

  k1_stats<<<BB, 256, 0, stream>>>(de, dw, db_, pw, pwb, part, x2h, useWs);
  k2_bn1<<<CC, 256, 0, stream>>>(part, bn1g, bn1b, ws, gcw, gcf);
  k3_main<<<BB, 256, 0, stream>>>(de, dw, db_, pw, pwb, ws, gcf, fcw, fcb, hT, x2h, useWs);
  k4_bn2<<<CC, 256, 0, stream>>>(hT, bn2g, bn2b, ws);
  k5_out<<<BB / 256, 256, 0, stream>>>(hT, ws, clsw, clsb, out);
}